// Round 5
// baseline (765.211 us; speedup 1.0000x reference)
//
#include <hip/hip_runtime.h>

// Problem constants (fixed by setup_inputs)
#define BB 8
#define CC 64
#define HH 128
#define WW 512
#define SS 512
#define HALF 256
#define HWP (HH * WW)        // 65536
#define BHW (BB * HWP)       // 524288
#define CELLS (BB * SS * SS) // 2097152

// native clang vector (HIP float4 is a class -> rejected by nontemporal builtin)
typedef float vfloat4 __attribute__((ext_vector_type(4)));

__device__ __forceinline__ unsigned int order_f32(float f) {
    unsigned int u = __float_as_uint(f);
    return (u & 0x80000000u) ? ~u : (u | 0x80000000u);
}

// Kernel 2: project pixels, atomicMin packed (y, ~idx) key per cell.
__global__ __launch_bounds__(256) void proj_kernel(
    const float* __restrict__ camera_k,
    const float* __restrict__ depth,
    const float* __restrict__ mpp_p,
    unsigned long long* __restrict__ keys)
{
    __shared__ float sk[9];
    const int idx = blockIdx.x * 256 + threadIdx.x;   // all 256 pixels share one batch b
    const int b = idx >> 16;                          // HW = 65536

    if (threadIdx.x == 0) {
        const float rs[3] = {0.5f, 0.5f, 1.0f};
        double a[9];
        #pragma unroll
        for (int i = 0; i < 3; ++i)
            #pragma unroll
            for (int j = 0; j < 3; ++j)
                a[i*3 + j] = (double)__fmul_rn(camera_k[b*9 + i*3 + j], rs[i]);
        double det = a[0]*(a[4]*a[8]-a[5]*a[7])
                   - a[1]*(a[3]*a[8]-a[5]*a[6])
                   + a[2]*(a[3]*a[7]-a[4]*a[6]);
        double inv[9];
        inv[0] =  (a[4]*a[8]-a[5]*a[7])/det;
        inv[1] = -(a[1]*a[8]-a[2]*a[7])/det;
        inv[2] =  (a[1]*a[5]-a[2]*a[4])/det;
        inv[3] = -(a[3]*a[8]-a[5]*a[6])/det;
        inv[4] =  (a[0]*a[8]-a[2]*a[6])/det;
        inv[5] = -(a[0]*a[5]-a[2]*a[3])/det;
        inv[6] =  (a[3]*a[7]-a[4]*a[6])/det;
        inv[7] = -(a[0]*a[7]-a[1]*a[6])/det;
        inv[8] =  (a[0]*a[4]-a[1]*a[3])/det;
        #pragma unroll
        for (int i = 0; i < 9; ++i) sk[i] = (float)inv[i];
    }
    __syncthreads();

    const int rem = idx & (HWP - 1);
    const int v = rem >> 9;          // W = 512
    const int u = rem & (WW - 1);
    const float d = depth[idx];
    const float mpp = mpp_p[0];
    const float uf = (float)u, vf = (float)v;

    // Match numpy f32 semantics exactly: no FMA contraction on this chain.
    float xw = __fadd_rn(__fadd_rn(__fmul_rn(sk[0], uf), __fmul_rn(sk[1], vf)), sk[2]);
    float yw = __fadd_rn(__fadd_rn(__fmul_rn(sk[3], uf), __fmul_rn(sk[4], vf)), sk[5]);
    float zw = __fadd_rn(__fadd_rn(__fmul_rn(sk[6], uf), __fmul_rn(sk[7], vf)), sk[8]);
    float x3 = __fmul_rn(__fmul_rn(xw, d), 1.2f);
    float y3 = __fmul_rn(__fmul_rn(yw, d), 1.2f);
    float z3 = __fmul_rn(__fmul_rn(zw, d), 1.2f);

    int xi = (int)truncf(__fdiv_rn(x3, mpp));
    int zi = (int)truncf(__fdiv_rn(z3, mpp));

    if (xi >= -HALF && xi <= HALF - 1 && zi >= -HALF && zi <= HALF - 1) {
        int cell = (b << 18) | ((xi + HALF) << 9) | (zi + HALF);
        unsigned long long key =
            ((unsigned long long)order_f32(y3) << 32) | (unsigned int)(~idx);
        atomicMin(&keys[cell], key);
    }
}

// Kernel 2.5: compact u64 keys -> u32 winner rem (v*W+u within batch) or ~0.
// Halves the scatter's key traffic and lets it sit in L2.
__global__ __launch_bounds__(256) void pack_kernel(
    const unsigned long long* __restrict__ keys,
    unsigned int* __restrict__ win)
{
    const int i = blockIdx.x * 256 + threadIdx.x;   // handles 2 cells
    ulonglong2 k = ((const ulonglong2*)keys)[i];
    uint2 o;
    o.x = (k.x != ~0ull) ? ((~(unsigned int)k.x) & (HWP - 1)) : 0xFFFFFFFFu;
    o.y = (k.y != ~0ull) ? ((~(unsigned int)k.y) & (HWP - 1)) : 0xFFFFFFFFu;
    ((uint2*)win)[i] = o;
}

// Kernel 3: thread = (4 consecutive zz cells) x (8 channels).
// XCD-locality: with round-robin block->XCD dispatch (n%8), each XCD owns
// one 8-channel supergroup and sweeps all cells batch-by-batch. Active
// gather working set per XCD = 8 planes x 256 KB = 2 MB < 4 MiB L2, and
// every image plane is fetched by exactly one XCD (one HBM first-touch,
// ~64x line reuse served from L2). Output stores are nontemporal so the
// 512 MB write stream doesn't evict the gather lines.
__global__ __launch_bounds__(256) void scatter_kernel(
    const float* __restrict__ img,
    const unsigned int* __restrict__ win,
    float* __restrict__ out)
{
    const int n  = blockIdx.x;           // 0..16383
    const int sg = n & 7;                // supergroup (XCD-pinned), 8 channels
    const int qb = n >> 3;               // quad-block 0..2047 (sequential batches)

    const int q     = qb * 256 + threadIdx.x; // cell-quad id, 0..524287
    const int c0    = sg << 3;                // first of 8 channels
    const int cell0 = q << 2;
    const int b     = cell0 >> 18;
    const int local = cell0 & (SS * SS - 1);

    const uint4 w = ((const uint4*)win)[q];
    const unsigned int wv[4] = {w.x, w.y, w.z, w.w};

    const float* plane0 = img + ((size_t)(b * CC + c0)) * HWP;
    float*       op     = out + ((size_t)(b * CC + c0)) * (size_t)(SS * SS) + local;

    // 32 independent predicated gathers -> deep MLP, then 8 coalesced
    // nontemporal float4 stores (1 KiB/wave each).
    float v[8][4];
    #pragma unroll
    for (int c = 0; c < 8; ++c) {
        const float* pl = plane0 + (size_t)c * HWP;
        #pragma unroll
        for (int i = 0; i < 4; ++i)
            v[c][i] = (wv[i] != 0xFFFFFFFFu) ? pl[wv[i]] : 0.0f;
    }
    #pragma unroll
    for (int c = 0; c < 8; ++c) {
        vfloat4 f4 = {v[c][0], v[c][1], v[c][2], v[c][3]};
        __builtin_nontemporal_store(f4, (vfloat4*)(op + (size_t)c * (SS * SS)));
    }
}

extern "C" void kernel_launch(void* const* d_in, const int* in_sizes, int n_in,
                              void* d_out, int out_size, void* d_ws, size_t ws_size,
                              hipStream_t stream) {
    const float* img      = (const float*)d_in[0];
    const float* camera_k = (const float*)d_in[1];
    const float* depth    = (const float*)d_in[2];
    const float* mpp      = (const float*)d_in[3];

    unsigned long long* keys = (unsigned long long*)d_ws;
    unsigned int*       win  = (unsigned int*)((char*)d_ws + (size_t)CELLS * 8);

    // Empty-cell sentinel = 0xFFFF.. (no finite y maps to it).
    (void)hipMemsetAsync(keys, 0xFF, (size_t)CELLS * sizeof(unsigned long long), stream);

    proj_kernel<<<BHW / 256, 256, 0, stream>>>(camera_k, depth, mpp, keys);
    pack_kernel<<<CELLS / 2 / 256, 256, 0, stream>>>(keys, win);

    // 8 XCD slots x 2048 quad-blocks = 16384 blocks
    scatter_kernel<<<16384, 256, 0, stream>>>(img, win, (float*)d_out);
}